// Round 2
// baseline (481.754 us; speedup 1.0000x reference)
//
#include <hip/hip_runtime.h>
#include <hip/hip_bf16.h>

typedef __hip_bfloat16 bf16;
typedef short bf16x4v __attribute__((ext_vector_type(4)));
typedef short bf16x8v __attribute__((ext_vector_type(8)));
typedef float f32x4v __attribute__((ext_vector_type(4)));

union U8 { bf16 h[8]; bf16x8v v; };
union U4 { bf16 h[4]; bf16x4v v; };

#define MFMA(a, b, c) __builtin_amdgcn_mfma_f32_16x16x32_bf16((a), (b), (c), 0, 0, 0)

#define GLOAD_LDS16(gp, lp)                                         \
  __builtin_amdgcn_global_load_lds(                                 \
      (const __attribute__((address_space(1))) void*)(gp),          \
      (__attribute__((address_space(3))) void*)(lp), 16, 0, 0)
#define WAIT_VMCNT_2 asm volatile("s_waitcnt vmcnt(2)" ::: "memory")
#define WAIT_VMCNT_0 asm volatile("s_waitcnt vmcnt(0)" ::: "memory")
#define WAIT_LGKM_0 asm volatile("s_waitcnt lgkmcnt(0)" ::: "memory")
#define BARRIER __builtin_amdgcn_s_barrier()

// ---------------------------------------------------------------------------
// K0: transpose + f32->bf16 convert the four 512x512 weight matrices into
// [n][k] layout so MFMA B-fragments are contiguous 16B reads. WT=[4][512][512].
// ---------------------------------------------------------------------------
__global__ __launch_bounds__(1024) void conv_weights(
    const float* __restrict__ Wq, const float* __restrict__ Wk,
    const float* __restrict__ Wv, const float* __restrict__ Wp,
    bf16* __restrict__ WT) {
  __shared__ float t[32][33];
  const float* srcs[4] = {Wq, Wk, Wv, Wp};
  const float* src = srcs[blockIdx.z];
  int k0 = blockIdx.y * 32, n0 = blockIdx.x * 32;
  t[threadIdx.y][threadIdx.x] = src[(size_t)(k0 + threadIdx.y) * 512 + n0 + threadIdx.x];
  __syncthreads();
  WT[((size_t)blockIdx.z * 512 + n0 + threadIdx.y) * 512 + k0 + threadIdx.x] =
      (bf16)t[threadIdx.x][threadIdx.y];
}

// ---------------------------------------------------------------------------
// K0c: fragment-pack Wp for the attn epilogue's out-projection.
// B-frag f = dtile*16 + kk (dtile 0..31 over d, kk 0..15 over 32-k chunks):
// Wpf[f*512 + lane*8 + e] = Wp[k = kk*32 + (lane>>4)*8 + e][d = dtile*16 + (lane&15)]
// (read from WTp = Wp transposed [d][k]). Each frag = contiguous 1KB wave load.
// ---------------------------------------------------------------------------
__global__ __launch_bounds__(256) void pack_wp(const bf16* __restrict__ WTp,
                                               bf16* __restrict__ Wpf) {
  const int f = blockIdx.x * 4 + (threadIdx.x >> 6);  // 512 frags
  const int lane = threadIdx.x & 63, quad = lane >> 4, l15 = lane & 15;
  const int dtile = f >> 4, kk = f & 15;
  bf16x8v v = *(const bf16x8v*)&WTp[(size_t)(dtile * 16 + l15) * 512 + kk * 32 + quad * 8];
  *(bf16x8v*)&Wpf[(size_t)f * 512 + lane * 8] = v;
}

// ---------------------------------------------------------------------------
// K0b: convert X (8*2048*512 f32) to canonical bf16 (parked in the Y region
// of d_out; consumed by qkv_gemm before the attn epilogue overwrites Y).
// ---------------------------------------------------------------------------
__global__ __launch_bounds__(256) void conv_x(const float* __restrict__ x,
                                              bf16* __restrict__ Xb) {
  size_t base = ((size_t)blockIdx.x * 256 + threadIdx.x) * 8;
  f32x4v a = *(const f32x4v*)(x + base);
  f32x4v b = *(const f32x4v*)(x + base + 4);
  U8 u;
#pragma unroll
  for (int e = 0; e < 4; e++) {
    u.h[e] = (bf16)a[e];
    u.h[4 + e] = (bf16)b[e];
  }
  *(bf16x8v*)(Xb + base) = u.v;
}

// ---------------------------------------------------------------------------
// K1: QKV projection GEMM. OUT[m][n] = sum_k Xb[m][k]*WT[n][k] + bias[n].
// 128x128 tile, BK=32, 256 threads (4 waves, 2x2 of 64x64).
// blockIdx.z selects Q / K / V. V is written FRAGMENT-PACKED (see round 1).
// ---------------------------------------------------------------------------
__global__ __launch_bounds__(256) void qkv_gemm(
    const bf16* __restrict__ Xb, const bf16* __restrict__ WTall,
    const float* __restrict__ bq, const float* __restrict__ bk,
    const float* __restrict__ bv,
    bf16* __restrict__ Q, bf16* __restrict__ Km, bf16* __restrict__ Vf) {
  const int which = blockIdx.z;
  const bf16* Wt = WTall + (size_t)which * 512 * 512;
  const float* bias = (which == 0) ? bq : (which == 1 ? bk : bv);
  const int n0 = blockIdx.x * 128;
  const int m0 = blockIdx.y * 128;
  __shared__ bf16 As[128][40];
  __shared__ bf16 Bs[128][40];
  const int tid = threadIdx.x;
  const int lane = tid & 63, w = tid >> 6;
  const int wr = w >> 1, wc = w & 1;
  const int quad = lane >> 4, l15 = lane & 15;

  f32x4v acc[4][4];
#pragma unroll
  for (int i = 0; i < 4; i++)
#pragma unroll
    for (int j = 0; j < 4; j++) acc[i][j] = (f32x4v){0.f, 0.f, 0.f, 0.f};

  const int srow = tid >> 2, scol = (tid & 3) * 8;
  for (int kt = 0; kt < 16; ++kt) {
    const int k0 = kt * 32;
#pragma unroll
    for (int it = 0; it < 2; ++it) {
      int r = srow + it * 64;
      *(bf16x8v*)&As[r][scol] = *(const bf16x8v*)&Xb[(size_t)(m0 + r) * 512 + k0 + scol];
      *(bf16x8v*)&Bs[r][scol] = *(const bf16x8v*)&Wt[(size_t)(n0 + r) * 512 + k0 + scol];
    }
    __syncthreads();
    bf16x8v a[4], b[4];
#pragma unroll
    for (int i = 0; i < 4; i++) a[i] = *(const bf16x8v*)&As[wr * 64 + i * 16 + l15][quad * 8];
#pragma unroll
    for (int j = 0; j < 4; j++) b[j] = *(const bf16x8v*)&Bs[wc * 64 + j * 16 + l15][quad * 8];
#pragma unroll
    for (int i = 0; i < 4; i++)
#pragma unroll
      for (int j = 0; j < 4; j++) acc[i][j] = MFMA(a[i], b[j], acc[i][j]);
    __syncthreads();
  }

#pragma unroll
  for (int j = 0; j < 4; j++) {
    int col = n0 + wc * 64 + j * 16 + l15;
    float bv_ = bias[col];
#pragma unroll
    for (int i = 0; i < 4; i++) {
      if (which == 2) {
        int row0 = m0 + wr * 64 + i * 16 + quad * 4;  // s for r=0; r adds +1..3
        int b_ = row0 >> 11, s_ = row0 & 2047;
        size_t fi = ((((size_t)b_ * 32 + (col >> 4)) * 64 + (s_ >> 5)) * 4 +
                     ((s_ >> 3) & 3)) * 128 +
                    (size_t)(col & 15) * 8 + (s_ & 7);
        U4 p4;
#pragma unroll
        for (int r = 0; r < 4; r++) p4.h[r] = (bf16)(acc[i][j][r] + bv_);
        *(bf16x4v*)(Vf + fi) = p4.v;  // 8-B aligned (s_&7 in {0,4})
      } else {
#pragma unroll
        for (int r = 0; r < 4; r++) {
          int row = m0 + wr * 64 + i * 16 + quad * 4 + r;
          float v = acc[i][j][r] + bv_;
          if (which == 0) Q[(size_t)row * 512 + col] = (bf16)v;
          else            Km[(size_t)row * 512 + col] = (bf16)v;
        }
      }
    }
  }
}

// ---------------------------------------------------------------------------
// K-chunk staging for attn phase 1 (unchanged from round 1).
// ---------------------------------------------------------------------------
__device__ __forceinline__ void stage_k(const bf16* __restrict__ Kb, char* kring,
                                        int c, int slot, int w, int lane) {
  const int stile = c & 31, dc = c >> 5;
  const bf16* gb = Kb + (size_t)stile * (64 * 512) + dc * 128;
  char* lb = kring + slot * 16384 + w * 2048;
#pragma unroll
  for (int i = 0; i < 2; i++) {
    const int R = (w * 2 + i) * 4 + (lane >> 4);      // row within 64-row tile
    const int segp = (lane & 15) ^ (R & 7);           // pre-swizzled 16B segment
    GLOAD_LDS16(gb + (size_t)R * 512 + segp * 8, lb + i * 1024);
  }
}

// ---------------------------------------------------------------------------
// K2 v4: fused attention + out-projection + residual + LayerNorm.
// One block = one (batch, 32-row Q-tile), 512 thr, batch XCD-pinned.
// Phase 1: S = Q K^T via 3-slot LDS ring (counted vmcnt, 1 barrier/chunk).
// Phase 2: exact softmax; attn f32 written from normalized registers.
// Phase 3: O = P V; Pst double-buffered, ONE barrier per stile; V from
//          fragment-packed global (1KB wave loads issued before the barrier).
// Epilogue: O-tile -> LDS (XOR-swizzled, reusing the dead K-ring), then
//          out = O @ Wp (+bp) + x residual, LayerNorm, write Y f32 directly.
//          Wave w owns d-cols [w*64, w*64+64): Wp frags read once per block.
// ---------------------------------------------------------------------------
__global__ __launch_bounds__(512, 2) void attn_kernel(
    const bf16* __restrict__ Q, const bf16* __restrict__ Km,
    const bf16* __restrict__ Vf, float* __restrict__ attn,
    const bf16* __restrict__ Wpf, const float* __restrict__ bp,
    const float* __restrict__ x, const float* __restrict__ gamma,
    const float* __restrict__ beta, float* __restrict__ Y) {
  __shared__ __align__(16) char smem[49152];        // K-ring (p1) / Os (epilogue)
  __shared__ float red[512];                        // 2 KB
  __shared__ __align__(16) bf16 Pst[2][32][72];     // 9.2 KB, 144-B rows

  const int b = blockIdx.x & 7;
  const int q0 = (blockIdx.x >> 3) << 5;
  const int tid = threadIdx.x, lane = tid & 63, w = tid >> 6;
  const int rg = w >> 2, cgi = w & 3;
  const int quad = lane >> 4, l15 = lane & 15;
  const float scale = 0.044194173824159216f;  // 1/sqrt(512)

  const bf16* Kb = Km + (size_t)b * 2048 * 512;

  // Q fragments direct from global (one-time; 16 x 16B per lane)
  bf16x8v a[16];
  {
    const bf16* qrow = Q + ((size_t)b * 2048 + q0 + rg * 16 + l15) * 512 + quad * 8;
#pragma unroll
    for (int kk = 0; kk < 16; kk++) a[kk] = *(const bf16x8v*)(qrow + kk * 32);
  }

  f32x4v acc[32];
#pragma unroll
  for (int st = 0; st < 32; st++) acc[st] = (f32x4v){0.f, 0.f, 0.f, 0.f};

  // ---- phase 1: S = Q K^T ----
  stage_k(Kb, smem, 0, 0, w, lane);
  stage_k(Kb, smem, 1, 1, w, lane);
  WAIT_VMCNT_0;  // drain Q loads + prologue stages (removes issue-order deps)
  BARRIER;

#pragma unroll
  for (int c = 0; c < 128; ++c) {
    WAIT_VMCNT_2;   // my chunk-c stage complete (chunk c+1 may stay in flight)
    WAIT_LGKM_0;    // my prior ds_reads retired (slot about to be re-staged)
    BARRIER;        // publish chunk c; license re-staging slot (c+2)%3
    const int cn = (c + 2 > 127) ? 127 : (c + 2);  // clamped re-stage: uniform vmcnt
    stage_k(Kb, smem, cn, (c + 2) % 3, w, lane);
    const int stile = c & 31, dc = c >> 5;  // dc-major: acc chains are only 4 deep
    const char* kb = (const char*)smem + (c % 3) * 16384 + (cgi * 16 + l15) * 256;
    f32x4v t = acc[stile];
#pragma unroll
    for (int kk = 0; kk < 4; kk++) {
      bf16x8v bfr = *(const bf16x8v*)(kb + (((kk * 4 + quad) ^ (l15 & 7)) << 4));
      t = MFMA(a[dc * 4 + kk], bfr, t);
    }
    acc[stile] = t;
  }
  WAIT_VMCNT_0;  // drain stray clamped stages (write dead ring slots only)
  BARRIER;

#pragma unroll
  for (int st = 0; st < 32; st++) acc[st] = acc[st] * scale;

  // ---- phase 2: softmax stats (l15 shuffles + cross-wave LDS reduce) ----
  float m[4], l[4];
#pragma unroll
  for (int r = 0; r < 4; r++) m[r] = -1e30f;
#pragma unroll
  for (int st = 0; st < 32; st++)
#pragma unroll
    for (int r = 0; r < 4; r++) m[r] = fmaxf(m[r], acc[st][r]);
#pragma unroll
  for (int off = 1; off < 16; off <<= 1)
#pragma unroll
    for (int r = 0; r < 4; r++) m[r] = fmaxf(m[r], __shfl_xor(m[r], off, 64));
  if (l15 == 0)
#pragma unroll
    for (int r = 0; r < 4; r++) red[rg * 64 + cgi * 16 + quad * 4 + r] = m[r];
  __syncthreads();
#pragma unroll
  for (int r = 0; r < 4; r++) {
    int row = rg * 64 + quad * 4 + r;
    float mm = red[row];
    for (int ww = 1; ww < 4; ww++) mm = fmaxf(mm, red[row + ww * 16]);
    m[r] = mm;
  }
#pragma unroll
  for (int r = 0; r < 4; r++) l[r] = 0.f;
#pragma unroll
  for (int st = 0; st < 32; st++)
#pragma unroll
    for (int r = 0; r < 4; r++) {
      float p = __expf(acc[st][r] - m[r]);
      acc[st][r] = p;
      l[r] += p;
    }
#pragma unroll
  for (int off = 1; off < 16; off <<= 1)
#pragma unroll
    for (int r = 0; r < 4; r++) l[r] += __shfl_xor(l[r], off, 64);
  if (l15 == 0)
#pragma unroll
    for (int r = 0; r < 4; r++) red[256 + rg * 64 + cgi * 16 + quad * 4 + r] = l[r];
  __syncthreads();
#pragma unroll
  for (int r = 0; r < 4; r++) {
    int row = 256 + rg * 64 + quad * 4 + r;
    float s_ = 0.f;
    for (int ww = 0; ww < 4; ww++) s_ += red[row + ww * 16];
    l[r] = 1.0f / s_;
  }

  // normalize in registers and write attn (f32) directly
#pragma unroll
  for (int st = 0; st < 32; st++) {
#pragma unroll
    for (int r = 0; r < 4; r++) {
      float p = acc[st][r] * l[r];
      acc[st][r] = p;
      attn[((size_t)(b * 2048) + q0 + rg * 16 + quad * 4 + r) * 2048 + st * 64 +
           cgi * 16 + l15] = p;
    }
  }

  // ---- phase 3: O = P V; double-buffered Pst, one barrier per stile ----
  f32x4v acc2[2][4];
#pragma unroll
  for (int hg = 0; hg < 2; hg++)
#pragma unroll
    for (int j = 0; j < 4; j++) acc2[hg][j] = (f32x4v){0.f, 0.f, 0.f, 0.f};
  const bf16* Vfb = Vf + (size_t)b * (1 << 20);  // 2 MB/batch, frag-packed
  const int w4 = w * 4;
  const int lane8 = lane * 8;

  // prologue: write P(0) into buffer 0
#pragma unroll
  for (int r = 0; r < 4; r++)
    Pst[0][rg * 16 + quad * 4 + r][cgi * 16 + l15] = (bf16)acc[0][r];

  for (int st = 0; st < 32; ++st) {
    WAIT_LGKM_0;  // my P-writes (st) and prior reads (st-1) retired
    BARRIER;      // publish P(st); licenses overwrite of buf (st+1)&1
    // prefetch this stile's 8 V fragments (contiguous 1 KB wave loads)
    bf16x8v vf[2][4];
#pragma unroll
    for (int ss = 0; ss < 2; ss++)
#pragma unroll
      for (int j = 0; j < 4; j++)
        vf[ss][j] = *(const bf16x8v*)(Vfb + ((size_t)(w4 + j) * 64 + st * 2 + ss) * 512 + lane8);
    const char* pb = (const char*)Pst[st & 1];
    bf16x8v a0[2], a1[2];
#pragma unroll
    for (int ss = 0; ss < 2; ss++) {
      a0[ss] = *(const bf16x8v*)(pb + l15 * 144 + ss * 64 + quad * 16);
      a1[ss] = *(const bf16x8v*)(pb + (16 + l15) * 144 + ss * 64 + quad * 16);
    }
    if (st < 31) {
#pragma unroll
      for (int r = 0; r < 4; r++)
        Pst[(st + 1) & 1][rg * 16 + quad * 4 + r][cgi * 16 + l15] =
            (bf16)acc[st + 1][r];
    }
#pragma unroll
    for (int ss = 0; ss < 2; ss++)
#pragma unroll
      for (int j = 0; j < 4; j++) {
        acc2[0][j] = MFMA(a0[ss], vf[ss][j], acc2[0][j]);
        acc2[1][j] = MFMA(a1[ss], vf[ss][j], acc2[1][j]);
      }
  }

  // ---- epilogue A: stage O-tile (bf16, XOR-swizzled) into Os (dead K-ring) ----
  bf16* Os = (bf16*)smem;  // 32 KB: 32 rows x 1024 B
#pragma unroll
  for (int hg = 0; hg < 2; hg++)
#pragma unroll
    for (int j = 0; j < 4; j++) {
      const int colb = (w * 64 + j * 16 + l15) * 2;
#pragma unroll
      for (int r = 0; r < 4; r++) {
        const int row = hg * 16 + quad * 4 + r;
        *(bf16*)((char*)Os + row * 1024 + (colb ^ ((row & 7) << 4))) =
            (bf16)acc2[hg][j][r];
      }
    }
  WAIT_LGKM_0;
  BARRIER;

  // ---- epilogue B: out = O @ Wp (+bp) + x residual, LayerNorm, write Y ----
  // wave w owns d-cols [w*64, w*64+64) for all 32 rows (Wp frags amp-1/block)
  f32x4v pacc[2][4];
#pragma unroll
  for (int rt = 0; rt < 2; rt++)
#pragma unroll
    for (int j2 = 0; j2 < 4; j2++) pacc[rt][j2] = (f32x4v){0.f, 0.f, 0.f, 0.f};
#pragma unroll 4
  for (int kk = 0; kk < 16; ++kk) {
    const int swz = (((kk * 4 + quad) ^ (l15 & 7)) << 4);
    bf16x8v af0 = *(const bf16x8v*)((const char*)Os + l15 * 1024 + swz);
    bf16x8v af1 = *(const bf16x8v*)((const char*)Os + (16 + l15) * 1024 + swz);
#pragma unroll
    for (int j2 = 0; j2 < 4; j2++) {
      bf16x8v bf_ = *(const bf16x8v*)(Wpf + ((size_t)(w4 + j2) * 16 + kk) * 512 + lane8);
      pacc[0][j2] = MFMA(af0, bf_, pacc[0][j2]);
      pacc[1][j2] = MFMA(af1, bf_, pacc[1][j2]);
    }
  }

  const float* xr = x + ((size_t)b * 2048 + q0) * 512;
  float s1[2][4], s2[2][4];
#pragma unroll
  for (int rt = 0; rt < 2; rt++)
#pragma unroll
    for (int r = 0; r < 4; r++) { s1[rt][r] = 0.f; s2[rt][r] = 0.f; }
#pragma unroll
  for (int rt = 0; rt < 2; rt++)
#pragma unroll
    for (int j2 = 0; j2 < 4; j2++) {
      const int col = w * 64 + j2 * 16 + l15;
      const float bpv = bp[col];
#pragma unroll
      for (int r = 0; r < 4; r++) {
        const int row = rt * 16 + quad * 4 + r;
        float v = pacc[rt][j2][r] + bpv + xr[(size_t)row * 512 + col];
        pacc[rt][j2][r] = v;
        s1[rt][r] += v;
        s2[rt][r] += v * v;
      }
    }
#pragma unroll
  for (int off = 1; off < 16; off <<= 1)
#pragma unroll
    for (int rt = 0; rt < 2; rt++)
#pragma unroll
      for (int r = 0; r < 4; r++) {
        s1[rt][r] += __shfl_xor(s1[rt][r], off, 64);
        s2[rt][r] += __shfl_xor(s2[rt][r], off, 64);
      }
  if (l15 == 0)
#pragma unroll
    for (int rt = 0; rt < 2; rt++)
#pragma unroll
      for (int r = 0; r < 4; r++) {
        red[w * 32 + rt * 16 + quad * 4 + r] = s1[rt][r];
        red[256 + w * 32 + rt * 16 + quad * 4 + r] = s2[rt][r];
      }
  __syncthreads();
  float mu[2][4], rs[2][4];
#pragma unroll
  for (int rt = 0; rt < 2; rt++)
#pragma unroll
    for (int r = 0; r < 4; r++) {
      const int row = rt * 16 + quad * 4 + r;
      float a1 = 0.f, a2 = 0.f;
      for (int ww = 0; ww < 8; ww++) {
        a1 += red[ww * 32 + row];
        a2 += red[256 + ww * 32 + row];
      }
      mu[rt][r] = a1 * (1.0f / 512.0f);
      float var = a2 * (1.0f / 512.0f) - mu[rt][r] * mu[rt][r];
      rs[rt][r] = rsqrtf(var + 1e-5f);
    }
  float* Yr = Y + ((size_t)b * 2048 + q0) * 512;
#pragma unroll
  for (int rt = 0; rt < 2; rt++)
#pragma unroll
    for (int j2 = 0; j2 < 4; j2++) {
      const int col = w * 64 + j2 * 16 + l15;
      const float g = gamma[col], be = beta[col];
#pragma unroll
      for (int r = 0; r < 4; r++) {
        const int row = rt * 16 + quad * 4 + r;
        Yr[(size_t)row * 512 + col] = (pacc[rt][j2][r] - mu[rt][r]) * rs[rt][r] * g + be;
      }
    }
}

// ---------------------------------------------------------------------------
extern "C" void kernel_launch(void* const* d_in, const int* in_sizes, int n_in,
                              void* d_out, int out_size, void* d_ws, size_t ws_size,
                              hipStream_t stream) {
  const float* x = (const float*)d_in[0];
  const float* Wq = (const float*)d_in[1];
  const float* bq = (const float*)d_in[2];
  const float* Wk = (const float*)d_in[3];
  const float* bk = (const float*)d_in[4];
  const float* Wv = (const float*)d_in[5];
  const float* bv = (const float*)d_in[6];
  const float* Wp = (const float*)d_in[7];
  const float* bp = (const float*)d_in[8];
  const float* gamma = (const float*)d_in[9];
  const float* beta = (const float*)d_in[10];

  char* ws = (char*)d_ws;
  bf16* WT = (bf16*)ws;                                      // 2 MB
  size_t off = 4ull * 512 * 512 * 2;
  bf16* Qd = (bf16*)(ws + off); off += 16384ull * 512 * 2;   // 16 MB
  bf16* Kd = (bf16*)(ws + off); off += 16384ull * 512 * 2;   // 16 MB
  bf16* Vfd = (bf16*)(ws + off); off += 16384ull * 512 * 2;  // 16 MB (frag-packed)
  bf16* Wpf = (bf16*)(ws + off); off += 512ull * 1024;       // 0.5 MB (frag-packed Wp)

  float* Y = (float*)d_out;                     // f32 [8][2048][512]
  float* attn = Y + 8ull * 2048 * 512;          // f32 [8][2048][2048]
  bf16* Xb = (bf16*)d_out;  // bf16 X parked in Y region (consumed by qkv_gemm)

  hipLaunchKernelGGL(conv_weights, dim3(16, 16, 4), dim3(32, 32), 0, stream,
                     Wq, Wk, Wv, Wp, WT);
  hipLaunchKernelGGL(pack_wp, dim3(128), dim3(256), 0, stream,
                     WT + 3ull * 512 * 512, Wpf);
  hipLaunchKernelGGL(conv_x, dim3(4096), dim3(256), 0, stream, x, Xb);
  hipLaunchKernelGGL(qkv_gemm, dim3(4, 128, 3), dim3(256), 0, stream,
                     Xb, WT, bq, bk, bv, Qd, Kd, Vfd);
  hipLaunchKernelGGL(attn_kernel, dim3(512), dim3(512), 0, stream,
                     Qd, Kd, Vfd, attn, Wpf, bp, x, gamma, beta, Y);
}

// Round 3
// 440.820 us; speedup vs baseline: 1.0929x; 1.0929x over previous
//
#include <hip/hip_runtime.h>
#include <hip/hip_bf16.h>

typedef __hip_bfloat16 bf16;
typedef short bf16x4v __attribute__((ext_vector_type(4)));
typedef short bf16x8v __attribute__((ext_vector_type(8)));
typedef float f32x4v __attribute__((ext_vector_type(4)));

union U8 { bf16 h[8]; bf16x8v v; };
union U4 { bf16 h[4]; bf16x4v v; };

#define MFMA(a, b, c) __builtin_amdgcn_mfma_f32_16x16x32_bf16((a), (b), (c), 0, 0, 0)

#define GLOAD_LDS16(gp, lp)                                         \
  __builtin_amdgcn_global_load_lds(                                 \
      (const __attribute__((address_space(1))) void*)(gp),          \
      (__attribute__((address_space(3))) void*)(lp), 16, 0, 0)
#define WAIT_VMCNT_2 asm volatile("s_waitcnt vmcnt(2)" ::: "memory")
#define WAIT_VMCNT_0 asm volatile("s_waitcnt vmcnt(0)" ::: "memory")
#define WAIT_LGKM_0 asm volatile("s_waitcnt lgkmcnt(0)" ::: "memory")
#define BARRIER __builtin_amdgcn_s_barrier()

// ---------------------------------------------------------------------------
// K0: transpose + f32->bf16 convert the four 512x512 weight matrices into
// [n][k] layout (WT=[4][512][512]). For z==3 (Wp) ALSO emit the
// fragment-packed Wpf used by the attn epilogue (pack_wp merged here):
//   f = (d>>4)*16 + (k>>5); lane = ((k>>3)&3)*16 + (d&15); elem = k&7
//   Wpf[f*512 + lane*8 + elem] = Wp[k][d]
// ---------------------------------------------------------------------------
__global__ __launch_bounds__(1024) void conv_weights(
    const float* __restrict__ Wq, const float* __restrict__ Wk,
    const float* __restrict__ Wv, const float* __restrict__ Wp,
    bf16* __restrict__ WT, bf16* __restrict__ Wpf) {
  __shared__ float t[32][33];
  const float* srcs[4] = {Wq, Wk, Wv, Wp};
  const float* src = srcs[blockIdx.z];
  int k0 = blockIdx.y * 32, n0 = blockIdx.x * 32;
  t[threadIdx.y][threadIdx.x] = src[(size_t)(k0 + threadIdx.y) * 512 + n0 + threadIdx.x];
  __syncthreads();
  float v = t[threadIdx.x][threadIdx.y];  // = src[k0+tx][n0+ty]
  WT[((size_t)blockIdx.z * 512 + n0 + threadIdx.y) * 512 + k0 + threadIdx.x] = (bf16)v;
  if (blockIdx.z == 3) {
    const int k = k0 + threadIdx.x, d = n0 + threadIdx.y;
    const int f = (d >> 4) * 16 + (k >> 5);
    const int lane = ((k >> 3) & 3) * 16 + (d & 15);
    Wpf[(size_t)f * 512 + lane * 8 + (k & 7)] = (bf16)v;
  }
}

// ---------------------------------------------------------------------------
// K0b: convert X (8*2048*512 f32) to canonical bf16 (parked in the Y region
// of d_out; consumed by qkv_gemm before the attn epilogue overwrites Y).
// ---------------------------------------------------------------------------
__global__ __launch_bounds__(256) void conv_x(const float* __restrict__ x,
                                              bf16* __restrict__ Xb) {
  size_t base = ((size_t)blockIdx.x * 256 + threadIdx.x) * 8;
  f32x4v a = *(const f32x4v*)(x + base);
  f32x4v b = *(const f32x4v*)(x + base + 4);
  U8 u;
#pragma unroll
  for (int e = 0; e < 4; e++) {
    u.h[e] = (bf16)a[e];
    u.h[4 + e] = (bf16)b[e];
  }
  *(bf16x8v*)(Xb + base) = u.v;
}

// ---------------------------------------------------------------------------
// K1 v2: QKV projection GEMM, 2-phase pipelined.
// OUT[m][n] = sum_k Xb[m][k]*WT[n][k] + bias[n]. 128x128 tile, BK=32,
// 256 threads (4 waves, 2x2 of 64x64). Double-buffered LDS; tile kt+1 is
// loaded to registers BEFORE the MFMAs of kt and ds_written after them;
// ONE barrier per K-step (each wave waits its own lgkm before the barrier,
// so buffer^1's prior readers are provably done).
// blockIdx.z selects Q / K / V. V is written FRAGMENT-PACKED (see round 1).
// ---------------------------------------------------------------------------
__global__ __launch_bounds__(256) void qkv_gemm(
    const bf16* __restrict__ Xb, const bf16* __restrict__ WTall,
    const float* __restrict__ bq, const float* __restrict__ bk,
    const float* __restrict__ bv,
    bf16* __restrict__ Q, bf16* __restrict__ Km, bf16* __restrict__ Vf) {
  const int which = blockIdx.z;
  const bf16* Wt = WTall + (size_t)which * 512 * 512;
  const float* bias = (which == 0) ? bq : (which == 1 ? bk : bv);
  const int n0 = blockIdx.x * 128;
  const int m0 = blockIdx.y * 128;
  __shared__ bf16 As[2][128][40];
  __shared__ bf16 Bs[2][128][40];
  const int tid = threadIdx.x;
  const int lane = tid & 63, w = tid >> 6;
  const int wr = w >> 1, wc = w & 1;
  const int quad = lane >> 4, l15 = lane & 15;

  f32x4v acc[4][4];
#pragma unroll
  for (int i = 0; i < 4; i++)
#pragma unroll
    for (int j = 0; j < 4; j++) acc[i][j] = (f32x4v){0.f, 0.f, 0.f, 0.f};

  const int srow = tid >> 2, scol = (tid & 3) * 8;
  const bf16* xr0 = &Xb[(size_t)(m0 + srow) * 512 + scol];
  const bf16* xr1 = &Xb[(size_t)(m0 + srow + 64) * 512 + scol];
  const bf16* wr0 = &Wt[(size_t)(n0 + srow) * 512 + scol];
  const bf16* wr1 = &Wt[(size_t)(n0 + srow + 64) * 512 + scol];

  // prologue: stage kt=0 into buffer 0
  {
    bf16x8v gA0 = *(const bf16x8v*)xr0;
    bf16x8v gA1 = *(const bf16x8v*)xr1;
    bf16x8v gB0 = *(const bf16x8v*)wr0;
    bf16x8v gB1 = *(const bf16x8v*)wr1;
    *(bf16x8v*)&As[0][srow][scol] = gA0;
    *(bf16x8v*)&As[0][srow + 64][scol] = gA1;
    *(bf16x8v*)&Bs[0][srow][scol] = gB0;
    *(bf16x8v*)&Bs[0][srow + 64][scol] = gB1;
  }
  WAIT_LGKM_0;
  BARRIER;

  for (int kt = 0; kt < 16; ++kt) {
    const int cur = kt & 1;
    bf16x8v gA0, gA1, gB0, gB1;
    if (kt < 15) {  // issue next tile's global loads before the MFMAs
      const int k0n = (kt + 1) * 32;
      gA0 = *(const bf16x8v*)(xr0 + k0n);
      gA1 = *(const bf16x8v*)(xr1 + k0n);
      gB0 = *(const bf16x8v*)(wr0 + k0n);
      gB1 = *(const bf16x8v*)(wr1 + k0n);
    }
    bf16x8v a[4], b[4];
#pragma unroll
    for (int i = 0; i < 4; i++)
      a[i] = *(const bf16x8v*)&As[cur][wr * 64 + i * 16 + l15][quad * 8];
#pragma unroll
    for (int j = 0; j < 4; j++)
      b[j] = *(const bf16x8v*)&Bs[cur][wc * 64 + j * 16 + l15][quad * 8];
#pragma unroll
    for (int i = 0; i < 4; i++)
#pragma unroll
      for (int j = 0; j < 4; j++) acc[i][j] = MFMA(a[i], b[j], acc[i][j]);
    if (kt < 15) {
      *(bf16x8v*)&As[cur ^ 1][srow][scol] = gA0;
      *(bf16x8v*)&As[cur ^ 1][srow + 64][scol] = gA1;
      *(bf16x8v*)&Bs[cur ^ 1][srow][scol] = gB0;
      *(bf16x8v*)&Bs[cur ^ 1][srow + 64][scol] = gB1;
    }
    WAIT_LGKM_0;  // my ds_reads (cur) + ds_writes (cur^1) retired
    BARRIER;      // publish buffer cur^1
  }

#pragma unroll
  for (int j = 0; j < 4; j++) {
    int col = n0 + wc * 64 + j * 16 + l15;
    float bv_ = bias[col];
#pragma unroll
    for (int i = 0; i < 4; i++) {
      if (which == 2) {
        int row0 = m0 + wr * 64 + i * 16 + quad * 4;  // s for r=0; r adds +1..3
        int b_ = row0 >> 11, s_ = row0 & 2047;
        size_t fi = ((((size_t)b_ * 32 + (col >> 4)) * 64 + (s_ >> 5)) * 4 +
                     ((s_ >> 3) & 3)) * 128 +
                    (size_t)(col & 15) * 8 + (s_ & 7);
        U4 p4;
#pragma unroll
        for (int r = 0; r < 4; r++) p4.h[r] = (bf16)(acc[i][j][r] + bv_);
        *(bf16x4v*)(Vf + fi) = p4.v;  // 8-B aligned (s_&7 in {0,4})
      } else {
#pragma unroll
        for (int r = 0; r < 4; r++) {
          int row = m0 + wr * 64 + i * 16 + quad * 4 + r;
          float v = acc[i][j][r] + bv_;
          if (which == 0) Q[(size_t)row * 512 + col] = (bf16)v;
          else            Km[(size_t)row * 512 + col] = (bf16)v;
        }
      }
    }
  }
}

// ---------------------------------------------------------------------------
// K-chunk staging for attn phase 1 (unchanged; proven in rounds 1-2).
// ---------------------------------------------------------------------------
__device__ __forceinline__ void stage_k(const bf16* __restrict__ Kb, char* kring,
                                        int c, int slot, int w, int lane) {
  const int stile = c & 31, dc = c >> 5;
  const bf16* gb = Kb + (size_t)stile * (64 * 512) + dc * 128;
  char* lb = kring + slot * 16384 + w * 2048;
#pragma unroll
  for (int i = 0; i < 2; i++) {
    const int R = (w * 2 + i) * 4 + (lane >> 4);      // row within 64-row tile
    const int segp = (lane & 15) ^ (R & 7);           // pre-swizzled 16B segment
    GLOAD_LDS16(gb + (size_t)R * 512 + segp * 8, lb + i * 1024);
  }
}

// ---------------------------------------------------------------------------
// K2 v5: fused attention + out-projection + residual + LayerNorm.
// One block = one (batch, 32-row Q-tile), 512 thr, batch XCD-pinned.
// Occupancy note: acc[32] f32x4 = 128 AGPRs -> ~248 total regs -> 1 block/CU,
// 8 waves. Every vmem load must be issued with >= a barrier of cover.
// Phase 1: S = Q K^T via 3-slot LDS ring (counted vmcnt, 1 barrier/chunk).
// Phase 2: exact softmax; attn f32 written from normalized registers.
// Phase 3: O = P V; Pst double-buffered, ONE barrier per stile; V fragment
//          loads issued BEFORE the barrier (round-1 cover, round-2 cost).
// Epilogue: O-tile -> LDS (swizzled, reusing dead K-ring); out = O @ Wp with
//          ping-pong Wpf prefetch; + bp + x residual; LayerNorm; write Y.
// ---------------------------------------------------------------------------
__global__ __launch_bounds__(512, 2) void attn_kernel(
    const bf16* __restrict__ Q, const bf16* __restrict__ Km,
    const bf16* __restrict__ Vf, float* __restrict__ attn,
    const bf16* __restrict__ Wpf, const float* __restrict__ bp,
    const float* __restrict__ x, const float* __restrict__ gamma,
    const float* __restrict__ beta, float* __restrict__ Y) {
  __shared__ __align__(16) char smem[49152];        // K-ring (p1) / Os (epilogue)
  __shared__ float red[512];                        // 2 KB
  __shared__ __align__(16) bf16 Pst[2][32][72];     // 9.2 KB, 144-B rows

  const int b = blockIdx.x & 7;
  const int q0 = (blockIdx.x >> 3) << 5;
  const int tid = threadIdx.x, lane = tid & 63, w = tid >> 6;
  const int rg = w >> 2, cgi = w & 3;
  const int quad = lane >> 4, l15 = lane & 15;
  const float scale = 0.044194173824159216f;  // 1/sqrt(512)

  const bf16* Kb = Km + (size_t)b * 2048 * 512;

  // Q fragments direct from global (one-time; 16 x 16B per lane)
  bf16x8v a[16];
  {
    const bf16* qrow = Q + ((size_t)b * 2048 + q0 + rg * 16 + l15) * 512 + quad * 8;
#pragma unroll
    for (int kk = 0; kk < 16; kk++) a[kk] = *(const bf16x8v*)(qrow + kk * 32);
  }

  f32x4v acc[32];
#pragma unroll
  for (int st = 0; st < 32; st++) acc[st] = (f32x4v){0.f, 0.f, 0.f, 0.f};

  // ---- phase 1: S = Q K^T ----
  stage_k(Kb, smem, 0, 0, w, lane);
  stage_k(Kb, smem, 1, 1, w, lane);
  WAIT_VMCNT_0;  // drain Q loads + prologue stages (removes issue-order deps)
  BARRIER;

#pragma unroll
  for (int c = 0; c < 128; ++c) {
    WAIT_VMCNT_2;   // my chunk-c stage complete (chunk c+1 may stay in flight)
    WAIT_LGKM_0;    // my prior ds_reads retired (slot about to be re-staged)
    BARRIER;        // publish chunk c; license re-staging slot (c+2)%3
    const int cn = (c + 2 > 127) ? 127 : (c + 2);  // clamped re-stage: uniform vmcnt
    stage_k(Kb, smem, cn, (c + 2) % 3, w, lane);
    const int stile = c & 31, dc = c >> 5;  // dc-major: acc chains are only 4 deep
    const char* kb = (const char*)smem + (c % 3) * 16384 + (cgi * 16 + l15) * 256;
    f32x4v t = acc[stile];
#pragma unroll
    for (int kk = 0; kk < 4; kk++) {
      bf16x8v bfr = *(const bf16x8v*)(kb + (((kk * 4 + quad) ^ (l15 & 7)) << 4));
      t = MFMA(a[dc * 4 + kk], bfr, t);
    }
    acc[stile] = t;
  }
  WAIT_VMCNT_0;  // drain stray clamped stages (write dead ring slots only)
  BARRIER;

#pragma unroll
  for (int st = 0; st < 32; st++) acc[st] = acc[st] * scale;

  // ---- phase 2: softmax stats (l15 shuffles + cross-wave LDS reduce) ----
  float m[4], l[4];
#pragma unroll
  for (int r = 0; r < 4; r++) m[r] = -1e30f;
#pragma unroll
  for (int st = 0; st < 32; st++)
#pragma unroll
    for (int r = 0; r < 4; r++) m[r] = fmaxf(m[r], acc[st][r]);
#pragma unroll
  for (int off = 1; off < 16; off <<= 1)
#pragma unroll
    for (int r = 0; r < 4; r++) m[r] = fmaxf(m[r], __shfl_xor(m[r], off, 64));
  if (l15 == 0)
#pragma unroll
    for (int r = 0; r < 4; r++) red[rg * 64 + cgi * 16 + quad * 4 + r] = m[r];
  __syncthreads();
#pragma unroll
  for (int r = 0; r < 4; r++) {
    int row = rg * 64 + quad * 4 + r;
    float mm = red[row];
    for (int ww = 1; ww < 4; ww++) mm = fmaxf(mm, red[row + ww * 16]);
    m[r] = mm;
  }
#pragma unroll
  for (int r = 0; r < 4; r++) l[r] = 0.f;
#pragma unroll
  for (int st = 0; st < 32; st++)
#pragma unroll
    for (int r = 0; r < 4; r++) {
      float p = __expf(acc[st][r] - m[r]);
      acc[st][r] = p;
      l[r] += p;
    }
#pragma unroll
  for (int off = 1; off < 16; off <<= 1)
#pragma unroll
    for (int r = 0; r < 4; r++) l[r] += __shfl_xor(l[r], off, 64);
  if (l15 == 0)
#pragma unroll
    for (int r = 0; r < 4; r++) red[256 + rg * 64 + cgi * 16 + quad * 4 + r] = l[r];
  __syncthreads();
#pragma unroll
  for (int r = 0; r < 4; r++) {
    int row = 256 + rg * 64 + quad * 4 + r;
    float s_ = 0.f;
    for (int ww = 0; ww < 4; ww++) s_ += red[row + ww * 16];
    l[r] = 1.0f / s_;
  }

  // normalize in registers and write attn (f32) directly
#pragma unroll
  for (int st = 0; st < 32; st++) {
#pragma unroll
    for (int r = 0; r < 4; r++) {
      float p = acc[st][r] * l[r];
      acc[st][r] = p;
      attn[((size_t)(b * 2048) + q0 + rg * 16 + quad * 4 + r) * 2048 + st * 64 +
           cgi * 16 + l15] = p;
    }
  }

  // ---- phase 3: O = P V; double-buffered Pst, one barrier per stile;
  //      V fragments issued BEFORE the barrier so latency hides under it ----
  f32x4v acc2[2][4];
#pragma unroll
  for (int hg = 0; hg < 2; hg++)
#pragma unroll
    for (int j = 0; j < 4; j++) acc2[hg][j] = (f32x4v){0.f, 0.f, 0.f, 0.f};
  const bf16* Vfb = Vf + (size_t)b * (1 << 20);  // 2 MB/batch, frag-packed
  const int w4 = w * 4;
  const int lane8 = lane * 8;

  // prologue: write P(0) into buffer 0
#pragma unroll
  for (int r = 0; r < 4; r++)
    Pst[0][rg * 16 + quad * 4 + r][cgi * 16 + l15] = (bf16)acc[0][r];

  for (int st = 0; st < 32; ++st) {
    // issue this stile's 8 V fragments (contiguous 1 KB wave loads) EARLY
    bf16x8v vf[2][4];
#pragma unroll
    for (int ss = 0; ss < 2; ss++)
#pragma unroll
      for (int j = 0; j < 4; j++)
        vf[ss][j] = *(const bf16x8v*)(Vfb + ((size_t)(w4 + j) * 64 + st * 2 + ss) * 512 + lane8);
    WAIT_LGKM_0;  // my P-writes (st) and prior pb reads (st-1) retired
    BARRIER;      // publish P(st); licenses overwrite of buf (st+1)&1
    const char* pb = (const char*)Pst[st & 1];
    bf16x8v a0[2], a1[2];
#pragma unroll
    for (int ss = 0; ss < 2; ss++) {
      a0[ss] = *(const bf16x8v*)(pb + l15 * 144 + ss * 64 + quad * 16);
      a1[ss] = *(const bf16x8v*)(pb + (16 + l15) * 144 + ss * 64 + quad * 16);
    }
    if (st < 31) {
#pragma unroll
      for (int r = 0; r < 4; r++)
        Pst[(st + 1) & 1][rg * 16 + quad * 4 + r][cgi * 16 + l15] =
            (bf16)acc[st + 1][r];
    }
#pragma unroll
    for (int ss = 0; ss < 2; ss++)
#pragma unroll
      for (int j = 0; j < 4; j++) {
        acc2[0][j] = MFMA(a0[ss], vf[ss][j], acc2[0][j]);
        acc2[1][j] = MFMA(a1[ss], vf[ss][j], acc2[1][j]);
      }
  }

  // ---- epilogue A: stage O-tile (bf16, XOR-swizzled) into Os (dead K-ring);
  //      prefetch first Wpf frags before the barrier ----
  bf16* Os = (bf16*)smem;  // 32 KB: 32 rows x 1024 B
#pragma unroll
  for (int hg = 0; hg < 2; hg++)
#pragma unroll
    for (int j = 0; j < 4; j++) {
      const int colb = (w * 64 + j * 16 + l15) * 2;
#pragma unroll
      for (int r = 0; r < 4; r++) {
        const int row = hg * 16 + quad * 4 + r;
        *(bf16*)((char*)Os + row * 1024 + (colb ^ ((row & 7) << 4))) =
            (bf16)acc2[hg][j][r];
      }
    }
  bf16x8v bfq[2][4];
#pragma unroll
  for (int j2 = 0; j2 < 4; j2++)
    bfq[0][j2] = *(const bf16x8v*)(Wpf + ((size_t)(w4 + j2) * 16 + 0) * 512 + lane8);
  WAIT_LGKM_0;
  BARRIER;

  // ---- epilogue B: out = O @ Wp (+bp) + x residual, LayerNorm, write Y ----
  // wave w owns d-cols [w*64, w*64+64); Wpf ping-pong prefetch (distance 1)
  f32x4v pacc[2][4];
#pragma unroll
  for (int rt = 0; rt < 2; rt++)
#pragma unroll
    for (int j2 = 0; j2 < 4; j2++) pacc[rt][j2] = (f32x4v){0.f, 0.f, 0.f, 0.f};
#pragma unroll
  for (int kk = 0; kk < 16; ++kk) {
    if (kk < 15) {
#pragma unroll
      for (int j2 = 0; j2 < 4; j2++)
        bfq[(kk + 1) & 1][j2] =
            *(const bf16x8v*)(Wpf + ((size_t)(w4 + j2) * 16 + kk + 1) * 512 + lane8);
    }
    const int swz = (((kk * 4 + quad) ^ (l15 & 7)) << 4);
    bf16x8v af0 = *(const bf16x8v*)((const char*)Os + l15 * 1024 + swz);
    bf16x8v af1 = *(const bf16x8v*)((const char*)Os + (16 + l15) * 1024 + swz);
#pragma unroll
    for (int j2 = 0; j2 < 4; j2++) {
      pacc[0][j2] = MFMA(af0, bfq[kk & 1][j2], pacc[0][j2]);
      pacc[1][j2] = MFMA(af1, bfq[kk & 1][j2], pacc[1][j2]);
    }
  }

  const float* xr = x + ((size_t)b * 2048 + q0) * 512;
  float s1[2][4], s2[2][4];
#pragma unroll
  for (int rt = 0; rt < 2; rt++)
#pragma unroll
    for (int r = 0; r < 4; r++) { s1[rt][r] = 0.f; s2[rt][r] = 0.f; }
#pragma unroll
  for (int rt = 0; rt < 2; rt++)
#pragma unroll
    for (int j2 = 0; j2 < 4; j2++) {
      const int col = w * 64 + j2 * 16 + l15;
      const float bpv = bp[col];
#pragma unroll
      for (int r = 0; r < 4; r++) {
        const int row = rt * 16 + quad * 4 + r;
        float v = pacc[rt][j2][r] + bpv + xr[(size_t)row * 512 + col];
        pacc[rt][j2][r] = v;
        s1[rt][r] += v;
        s2[rt][r] += v * v;
      }
    }
#pragma unroll
  for (int off = 1; off < 16; off <<= 1)
#pragma unroll
    for (int rt = 0; rt < 2; rt++)
#pragma unroll
      for (int r = 0; r < 4; r++) {
        s1[rt][r] += __shfl_xor(s1[rt][r], off, 64);
        s2[rt][r] += __shfl_xor(s2[rt][r], off, 64);
      }
  if (l15 == 0)
#pragma unroll
    for (int rt = 0; rt < 2; rt++)
#pragma unroll
      for (int r = 0; r < 4; r++) {
        red[w * 32 + rt * 16 + quad * 4 + r] = s1[rt][r];
        red[256 + w * 32 + rt * 16 + quad * 4 + r] = s2[rt][r];
      }
  __syncthreads();
  float mu[2][4], rs[2][4];
#pragma unroll
  for (int rt = 0; rt < 2; rt++)
#pragma unroll
    for (int r = 0; r < 4; r++) {
      const int row = rt * 16 + quad * 4 + r;
      float a1 = 0.f, a2 = 0.f;
      for (int ww = 0; ww < 8; ww++) {
        a1 += red[ww * 32 + row];
        a2 += red[256 + ww * 32 + row];
      }
      mu[rt][r] = a1 * (1.0f / 512.0f);
      float var = a2 * (1.0f / 512.0f) - mu[rt][r] * mu[rt][r];
      rs[rt][r] = rsqrtf(var + 1e-5f);
    }
  float* Yr = Y + ((size_t)b * 2048 + q0) * 512;
#pragma unroll
  for (int rt = 0; rt < 2; rt++)
#pragma unroll
    for (int j2 = 0; j2 < 4; j2++) {
      const int col = w * 64 + j2 * 16 + l15;
      const float g = gamma[col], be = beta[col];
#pragma unroll
      for (int r = 0; r < 4; r++) {
        const int row = rt * 16 + quad * 4 + r;
        Yr[(size_t)row * 512 + col] = (pacc[rt][j2][r] - mu[rt][r]) * rs[rt][r] * g + be;
      }
    }
}

// ---------------------------------------------------------------------------
extern "C" void kernel_launch(void* const* d_in, const int* in_sizes, int n_in,
                              void* d_out, int out_size, void* d_ws, size_t ws_size,
                              hipStream_t stream) {
  const float* x = (const float*)d_in[0];
  const float* Wq = (const float*)d_in[1];
  const float* bq = (const float*)d_in[2];
  const float* Wk = (const float*)d_in[3];
  const float* bk = (const float*)d_in[4];
  const float* Wv = (const float*)d_in[5];
  const float* bv = (const float*)d_in[6];
  const float* Wp = (const float*)d_in[7];
  const float* bp = (const float*)d_in[8];
  const float* gamma = (const float*)d_in[9];
  const float* beta = (const float*)d_in[10];

  char* ws = (char*)d_ws;
  bf16* WT = (bf16*)ws;                                      // 2 MB
  size_t off = 4ull * 512 * 512 * 2;
  bf16* Qd = (bf16*)(ws + off); off += 16384ull * 512 * 2;   // 16 MB
  bf16* Kd = (bf16*)(ws + off); off += 16384ull * 512 * 2;   // 16 MB
  bf16* Vfd = (bf16*)(ws + off); off += 16384ull * 512 * 2;  // 16 MB (frag-packed)
  bf16* Wpf = (bf16*)(ws + off); off += 512ull * 1024;       // 0.5 MB (frag-packed Wp)

  float* Y = (float*)d_out;                     // f32 [8][2048][512]
  float* attn = Y + 8ull * 2048 * 512;          // f32 [8][2048][2048]
  bf16* Xb = (bf16*)d_out;  // bf16 X parked in Y region (consumed by qkv_gemm)

  hipLaunchKernelGGL(conv_weights, dim3(16, 16, 4), dim3(32, 32), 0, stream,
                     Wq, Wk, Wv, Wp, WT, Wpf);
  hipLaunchKernelGGL(conv_x, dim3(4096), dim3(256), 0, stream, x, Xb);
  hipLaunchKernelGGL(qkv_gemm, dim3(4, 128, 3), dim3(256), 0, stream,
                     Xb, WT, bq, bk, bv, Qd, Kd, Vfd);
  hipLaunchKernelGGL(attn_kernel, dim3(512), dim3(512), 0, stream,
                     Qd, Kd, Vfd, attn, Wpf, bp, x, gamma, beta, Y);
}

// Round 4
// 391.531 us; speedup vs baseline: 1.2304x; 1.1259x over previous
//
#include <hip/hip_runtime.h>
#include <hip/hip_bf16.h>

typedef __hip_bfloat16 bf16;
typedef short bf16x4v __attribute__((ext_vector_type(4)));
typedef short bf16x8v __attribute__((ext_vector_type(8)));
typedef float f32x4v __attribute__((ext_vector_type(4)));

union U8 { bf16 h[8]; bf16x8v v; };
union U4 { bf16 h[4]; bf16x4v v; };

#define MFMA(a, b, c) __builtin_amdgcn_mfma_f32_16x16x32_bf16((a), (b), (c), 0, 0, 0)

#define GLOAD_LDS16(gp, lp)                                         \
  __builtin_amdgcn_global_load_lds(                                 \
      (const __attribute__((address_space(1))) void*)(gp),          \
      (__attribute__((address_space(3))) void*)(lp), 16, 0, 0)
#define WAIT_VMCNT_4 asm volatile("s_waitcnt vmcnt(4)" ::: "memory")
#define WAIT_VMCNT_0 asm volatile("s_waitcnt vmcnt(0)" ::: "memory")
#define WAIT_LGKM_0 asm volatile("s_waitcnt lgkmcnt(0)" ::: "memory")
#define BARRIER __builtin_amdgcn_s_barrier()

// ---------------------------------------------------------------------------
// K0 "prep": one launch doing (a) weight transpose+convert WT=[4][512][512]
// (+ fragment-packed Wpf for z==3), and (b) X f32->bf16 conversion.
// Blocks [0,1024): weights (z = bx>>8, 32x32 tile). Blocks [1024,2048): X.
// ---------------------------------------------------------------------------
__global__ __launch_bounds__(1024) void prep(
    const float* __restrict__ Wq, const float* __restrict__ Wk,
    const float* __restrict__ Wv, const float* __restrict__ Wp,
    const float* __restrict__ x, bf16* __restrict__ WT,
    bf16* __restrict__ Wpf, bf16* __restrict__ Xb) {
  const int bx = blockIdx.x;
  if (bx < 1024) {
    __shared__ float t[32][33];
    const float* srcs[4] = {Wq, Wk, Wv, Wp};
    const int z = bx >> 8, rem = bx & 255;
    const int k0 = (rem >> 4) * 32, n0 = (rem & 15) * 32;
    const int ty = threadIdx.x >> 5, tx = threadIdx.x & 31;
    t[ty][tx] = srcs[z][(size_t)(k0 + ty) * 512 + n0 + tx];
    __syncthreads();
    float v = t[tx][ty];  // = W[k0+tx][n0+ty]
    WT[((size_t)z * 512 + n0 + ty) * 512 + k0 + tx] = (bf16)v;
    if (z == 3) {
      const int k = k0 + tx, d = n0 + ty;
      const int f = (d >> 4) * 16 + (k >> 5);
      const int lane = ((k >> 3) & 3) * 16 + (d & 15);
      Wpf[(size_t)f * 512 + lane * 8 + (k & 7)] = (bf16)v;
    }
  } else {
    size_t base = ((size_t)(bx - 1024) * 1024 + threadIdx.x) * 8;
    f32x4v a = *(const f32x4v*)(x + base);
    f32x4v b = *(const f32x4v*)(x + base + 4);
    U8 u;
#pragma unroll
    for (int e = 0; e < 4; e++) {
      u.h[e] = (bf16)a[e];
      u.h[4 + e] = (bf16)b[e];
    }
    *(bf16x8v*)(Xb + base) = u.v;
  }
}

// ---------------------------------------------------------------------------
// K1 v3: QKV projection GEMM, m97-style global_load_lds staging.
// OUT[m][n] = sum_k Xb[m][k]*WT[n][k] + bias[n]. 128x128 tile, BK=32,
// 256 threads (4 waves, 2x2 of 64x64). 3-slot LDS ring (As 8KB + Bs 8KB per
// slot, LINEAR layout), staged via global_load_lds with XOR segment swizzle
// (seg ^= (row>>1)&3, applied on BOTH the per-lane global source and the
// ds_read offset -> 2-way bank aliasing = free). Counted vmcnt(4): stage for
// kt+1 stays in flight across the barrier. One barrier per K-step.
// blockIdx.z selects Q / K / V. V is written FRAGMENT-PACKED (see round 1).
// ---------------------------------------------------------------------------
__global__ __launch_bounds__(256) void qkv_gemm(
    const bf16* __restrict__ Xb, const bf16* __restrict__ WTall,
    const float* __restrict__ bq, const float* __restrict__ bk,
    const float* __restrict__ bv,
    bf16* __restrict__ Q, bf16* __restrict__ Km, bf16* __restrict__ Vf) {
  __shared__ __align__(16) bf16 ring[3][8192];  // 3 x 16 KB
  const int which = blockIdx.z;
  const bf16* Wt = WTall + (size_t)which * 512 * 512;
  const float* bias = (which == 0) ? bq : (which == 1 ? bk : bv);
  const int n0 = blockIdx.x * 128;
  const int m0 = blockIdx.y * 128;
  const int tid = threadIdx.x;
  const int lane = tid & 63, w = tid >> 6;
  const int wr = w >> 1, wc = w & 1;
  const int quad = lane >> 4, l15 = lane & 15;

  f32x4v acc[4][4];
#pragma unroll
  for (int i = 0; i < 4; i++)
#pragma unroll
    for (int j = 0; j < 4; j++) acc[i][j] = (f32x4v){0.f, 0.f, 0.f, 0.f};

  // staging geometry: per wave, load i covers rows (i*4+w)*16 .. +16
  // (1 KB = 16 rows x 64 B); lane l -> row +(l>>2), seg l&3.
  const int segg = ((lane & 3) ^ ((lane >> 3) & 3)) * 8;  // pre-swizzled, elems
  const bf16* xb0 = Xb + (size_t)m0 * 512;
  const bf16* wb0 = Wt + (size_t)n0 * 512;

#define QKV_STAGE(kt_, slot_)                                                 \
  {                                                                           \
    const int k0_ = (kt_) * 32;                                               \
    char* sb_ = (char*)ring[(slot_)];                                         \
    _Pragma("unroll") for (int i = 0; i < 2; i++) {                           \
      const int R_ = (i * 4 + w) * 16 + (lane >> 2);                          \
      GLOAD_LDS16(xb0 + (size_t)R_ * 512 + k0_ + segg,                        \
                  sb_ + (i * 4 + w) * 1024);                                  \
      GLOAD_LDS16(wb0 + (size_t)R_ * 512 + k0_ + segg,                        \
                  sb_ + 8192 + (i * 4 + w) * 1024);                           \
    }                                                                         \
  }

  QKV_STAGE(0, 0);
  QKV_STAGE(1, 1);

  const int sxa = ((l15 >> 1) & 3);  // read-side seg XOR
  for (int kt = 0; kt < 16; ++kt) {
    WAIT_VMCNT_4;  // stage kt complete (stage kt+1 may stay in flight)
    WAIT_LGKM_0;
    BARRIER;       // publish slot kt%3; license re-stage of slot (kt+2)%3
    const int nk = (kt + 2 > 15) ? 15 : (kt + 2);
    QKV_STAGE(nk, (kt + 2) % 3);
    const char* As_ = (const char*)ring[kt % 3];
    bf16x8v a[4], b[4];
#pragma unroll
    for (int i = 0; i < 4; i++)
      a[i] = *(const bf16x8v*)(As_ + (wr * 64 + i * 16 + l15) * 64 +
                               ((quad ^ sxa) << 4));
#pragma unroll
    for (int j = 0; j < 4; j++)
      b[j] = *(const bf16x8v*)(As_ + 8192 + (wc * 64 + j * 16 + l15) * 64 +
                               ((quad ^ sxa) << 4));
#pragma unroll
    for (int i = 0; i < 4; i++)
#pragma unroll
      for (int j = 0; j < 4; j++) acc[i][j] = MFMA(a[i], b[j], acc[i][j]);
  }
#undef QKV_STAGE

#pragma unroll
  for (int j = 0; j < 4; j++) {
    int col = n0 + wc * 64 + j * 16 + l15;
    float bv_ = bias[col];
#pragma unroll
    for (int i = 0; i < 4; i++) {
      if (which == 2) {
        int row0 = m0 + wr * 64 + i * 16 + quad * 4;  // s for r=0; r adds +1..3
        int b_ = row0 >> 11, s_ = row0 & 2047;
        size_t fi = ((((size_t)b_ * 32 + (col >> 4)) * 64 + (s_ >> 5)) * 4 +
                     ((s_ >> 3) & 3)) * 128 +
                    (size_t)(col & 15) * 8 + (s_ & 7);
        U4 p4;
#pragma unroll
        for (int r = 0; r < 4; r++) p4.h[r] = (bf16)(acc[i][j][r] + bv_);
        *(bf16x4v*)(Vf + fi) = p4.v;  // 8-B aligned (s_&7 in {0,4})
      } else {
#pragma unroll
        for (int r = 0; r < 4; r++) {
          int row = m0 + wr * 64 + i * 16 + quad * 4 + r;
          float v = acc[i][j][r] + bv_;
          if (which == 0) Q[(size_t)row * 512 + col] = (bf16)v;
          else            Km[(size_t)row * 512 + col] = (bf16)v;
        }
      }
    }
  }
}

// ---------------------------------------------------------------------------
// attn phase-1 K staging: chunk c = (stile = c&31, dhalf = c>>5) is
// K[stile*64 .. +64][dhalf*256 .. +256] = 32 KB into a 3-slot ring.
// LDS linear (rows of 512 B); bank swizzle seg ^= row&7 applied via the
// per-lane pre-swizzled GLOBAL source (both-sides rule).
// Per wave: 4 loads, each 1 KB = 2 rows; load i covers rows (i*8+w)*2 .. +2.
// ---------------------------------------------------------------------------
__device__ __forceinline__ void stage_k2(const bf16* __restrict__ Kb, char* ring,
                                         int c, int slot, int w, int lane) {
  const int stile = c & 31, dhalf = c >> 5;
  const bf16* gb = Kb + (size_t)stile * (64 * 512) + dhalf * 256;
  char* sb = ring + slot * 32768;
#pragma unroll
  for (int i = 0; i < 4; i++) {
    const int rp = (i * 8 + w) * 2;
    const int R = rp + (lane >> 5);
    const int seg = (lane & 31) ^ (R & 7);
    GLOAD_LDS16(gb + (size_t)R * 512 + seg * 8, sb + rp * 512);
  }
}

// ---------------------------------------------------------------------------
// K2 v6: fused attention + out-projection + residual + LayerNorm.
// One block = one (batch, 32-row Q-tile), 512 thr, batch XCD-pinned.
// 1 block/CU (unified-reg cap at ~252); all latency must hide in-pipeline.
// Phase 1: 64 chunks of 32 KB (64x256), 3-slot ring, counted vmcnt(4)
//          (2-chunk latency cover), 1 barrier/chunk, 8 MFMA/wave/chunk.
// Phase 2: softmax STATS ONLY (attn write deferred to phase 3).
// Phase 3: per stile: normalize + attn f32 store (spread over PV) + Pst
//          double-buffer write; V fragments PING-PONG prefetched (distance 1,
//          covered by the 16-MFMA block); one barrier per stile.
// Epilogue: O-tile -> LDS (swizzled, ring reused); out = O @ Wp (ping-pong
//          Wpf prefetch) + bp + x residual; LayerNorm; write Y f32.
// ---------------------------------------------------------------------------
__global__ __launch_bounds__(512, 2) void attn_kernel(
    const bf16* __restrict__ Q, const bf16* __restrict__ Km,
    const bf16* __restrict__ Vf, float* __restrict__ attn,
    const bf16* __restrict__ Wpf, const float* __restrict__ bp,
    const float* __restrict__ x, const float* __restrict__ gamma,
    const float* __restrict__ beta, float* __restrict__ Y) {
  __shared__ __align__(16) char smem[98304];        // 3x32 KB ring / Os (epilogue)
  __shared__ float red[512];                        // 2 KB
  __shared__ __align__(16) bf16 Pst[2][32][72];     // 9.2 KB, 144-B rows

  const int b = blockIdx.x & 7;
  const int q0 = (blockIdx.x >> 3) << 5;
  const int tid = threadIdx.x, lane = tid & 63, w = tid >> 6;
  const int rg = w >> 2, cgi = w & 3;
  const int quad = lane >> 4, l15 = lane & 15;
  const float scale = 0.044194173824159216f;  // 1/sqrt(512)

  const bf16* Kb = Km + (size_t)b * 2048 * 512;

  // Q fragments direct from global (one-time; 16 x 16B per lane)
  bf16x8v a[16];
  {
    const bf16* qrow = Q + ((size_t)b * 2048 + q0 + rg * 16 + l15) * 512 + quad * 8;
#pragma unroll
    for (int kk = 0; kk < 16; kk++) a[kk] = *(const bf16x8v*)(qrow + kk * 32);
  }

  f32x4v acc[32];
#pragma unroll
  for (int st = 0; st < 32; st++) acc[st] = (f32x4v){0.f, 0.f, 0.f, 0.f};

  // ---- phase 1: S = Q K^T ----
  stage_k2(Kb, smem, 0, 0, w, lane);
  stage_k2(Kb, smem, 1, 1, w, lane);
  WAIT_VMCNT_0;  // drain Q loads + prologue stages (removes issue-order deps)
  BARRIER;

  const int sx7 = l15 & 7;
#pragma unroll
  for (int c = 0; c < 64; ++c) {
    WAIT_VMCNT_4;   // my chunk-c stage complete (chunk c+1 may stay in flight)
    WAIT_LGKM_0;    // my prior ds_reads retired (slot about to be re-staged)
    BARRIER;        // publish chunk c; license re-staging slot (c+2)%3
    const int cn = (c + 2 > 63) ? 63 : (c + 2);  // clamped re-stage: uniform vmcnt
    stage_k2(Kb, smem, cn, (c + 2) % 3, w, lane);
    const int stile = c & 31, dhalf = c >> 5;
    const char* kb = (const char*)smem + (c % 3) * 32768 + (cgi * 16 + l15) * 512;
    f32x4v t = acc[stile];
#pragma unroll
    for (int kk = 0; kk < 8; kk++) {
      bf16x8v bfr = *(const bf16x8v*)(kb + (((kk * 4 + quad) ^ sx7) << 4));
      t = MFMA(a[dhalf * 8 + kk], bfr, t);
    }
    acc[stile] = t;
  }
  WAIT_VMCNT_0;  // drain stray clamped stages (write dead ring slots only)
  BARRIER;

#pragma unroll
  for (int st = 0; st < 32; st++) acc[st] = acc[st] * scale;

  // ---- phase 2: softmax stats (l15 shuffles + cross-wave LDS reduce) ----
  float m[4], l[4];
#pragma unroll
  for (int r = 0; r < 4; r++) m[r] = -1e30f;
#pragma unroll
  for (int st = 0; st < 32; st++)
#pragma unroll
    for (int r = 0; r < 4; r++) m[r] = fmaxf(m[r], acc[st][r]);
#pragma unroll
  for (int off = 1; off < 16; off <<= 1)
#pragma unroll
    for (int r = 0; r < 4; r++) m[r] = fmaxf(m[r], __shfl_xor(m[r], off, 64));
  if (l15 == 0)
#pragma unroll
    for (int r = 0; r < 4; r++) red[rg * 64 + cgi * 16 + quad * 4 + r] = m[r];
  __syncthreads();
#pragma unroll
  for (int r = 0; r < 4; r++) {
    int row = rg * 64 + quad * 4 + r;
    float mm = red[row];
    for (int ww = 1; ww < 4; ww++) mm = fmaxf(mm, red[row + ww * 16]);
    m[r] = mm;
  }
#pragma unroll
  for (int r = 0; r < 4; r++) l[r] = 0.f;
#pragma unroll
  for (int st = 0; st < 32; st++)
#pragma unroll
    for (int r = 0; r < 4; r++) {
      float p = __expf(acc[st][r] - m[r]);
      acc[st][r] = p;   // unnormalized exp kept in regs
      l[r] += p;
    }
#pragma unroll
  for (int off = 1; off < 16; off <<= 1)
#pragma unroll
    for (int r = 0; r < 4; r++) l[r] += __shfl_xor(l[r], off, 64);
  if (l15 == 0)
#pragma unroll
    for (int r = 0; r < 4; r++) red[256 + rg * 64 + cgi * 16 + quad * 4 + r] = l[r];
  __syncthreads();
#pragma unroll
  for (int r = 0; r < 4; r++) {
    int row = 256 + rg * 64 + quad * 4 + r;
    float s_ = 0.f;
    for (int ww = 0; ww < 4; ww++) s_ += red[row + ww * 16];
    l[r] = 1.0f / s_;
  }

  // ---- phase 3: O = P V with normalize+attn-store interleaved ----
  f32x4v acc2[2][4];
#pragma unroll
  for (int hg = 0; hg < 2; hg++)
#pragma unroll
    for (int j = 0; j < 4; j++) acc2[hg][j] = (f32x4v){0.f, 0.f, 0.f, 0.f};
  const bf16* Vfb = Vf + (size_t)b * (1 << 20);  // 2 MB/batch, frag-packed
  const int w4 = w * 4;
  const int lane8 = lane * 8;
  float* attn_base = attn + ((size_t)(b * 2048) + q0 + rg * 16 + quad * 4) * 2048 +
                     cgi * 16 + l15;

  // prologue: normalize st=0, store attn row-chunk 0, write Pst[0], preload V(0)
#pragma unroll
  for (int r = 0; r < 4; r++) {
    float p = acc[0][r] * l[r];
    attn_base[(size_t)r * 2048] = p;
    Pst[0][rg * 16 + quad * 4 + r][cgi * 16 + l15] = (bf16)p;
  }
  bf16x8v vfp[2][2][4];
#pragma unroll
  for (int ss = 0; ss < 2; ss++)
#pragma unroll
    for (int j = 0; j < 4; j++)
      vfp[0][ss][j] = *(const bf16x8v*)(Vfb + ((size_t)(w4 + j) * 64 + ss) * 512 + lane8);

#pragma unroll
  for (int st = 0; st < 32; ++st) {
    const int cur = st & 1;
    WAIT_LGKM_0;  // my Pst writes (st) and prior reads (st-1) retired
    BARRIER;      // publish P(st); licenses overwrite of buf cur^1
    const char* pb = (const char*)Pst[cur];
    bf16x8v a0[2], a1[2];
#pragma unroll
    for (int ss = 0; ss < 2; ss++) {
      a0[ss] = *(const bf16x8v*)(pb + l15 * 144 + ss * 64 + quad * 16);
      a1[ss] = *(const bf16x8v*)(pb + (16 + l15) * 144 + ss * 64 + quad * 16);
    }
    if (st < 31) {
      // normalize + attn store + Pst write for st+1 (spreads the 134 MB write)
#pragma unroll
      for (int r = 0; r < 4; r++) {
        float p = acc[st + 1][r] * l[r];
        attn_base[(size_t)r * 2048 + (st + 1) * 64] = p;
        Pst[cur ^ 1][rg * 16 + quad * 4 + r][cgi * 16 + l15] = (bf16)p;
      }
      // ping-pong V prefetch for st+1 (covered by the MFMAs below)
#pragma unroll
      for (int ss = 0; ss < 2; ss++)
#pragma unroll
        for (int j = 0; j < 4; j++)
          vfp[cur ^ 1][ss][j] = *(const bf16x8v*)(
              Vfb + ((size_t)(w4 + j) * 64 + (st + 1) * 2 + ss) * 512 + lane8);
    }
#pragma unroll
    for (int ss = 0; ss < 2; ss++)
#pragma unroll
      for (int j = 0; j < 4; j++) {
        acc2[0][j] = MFMA(a0[ss], vfp[cur][ss][j], acc2[0][j]);
        acc2[1][j] = MFMA(a1[ss], vfp[cur][ss][j], acc2[1][j]);
      }
  }

  // ---- epilogue A: stage O-tile (bf16, XOR-swizzled) into Os (dead ring);
  //      prefetch first Wpf frags before the barrier ----
  bf16* Os = (bf16*)smem;  // 32 KB: 32 rows x 1024 B
#pragma unroll
  for (int hg = 0; hg < 2; hg++)
#pragma unroll
    for (int j = 0; j < 4; j++) {
      const int colb = (w * 64 + j * 16 + l15) * 2;
#pragma unroll
      for (int r = 0; r < 4; r++) {
        const int row = hg * 16 + quad * 4 + r;
        *(bf16*)((char*)Os + row * 1024 + (colb ^ ((row & 7) << 4))) =
            (bf16)acc2[hg][j][r];
      }
    }
  bf16x8v bfq[2][4];
#pragma unroll
  for (int j2 = 0; j2 < 4; j2++)
    bfq[0][j2] = *(const bf16x8v*)(Wpf + ((size_t)(w4 + j2) * 16 + 0) * 512 + lane8);
  WAIT_LGKM_0;
  BARRIER;

  // ---- epilogue B: out = O @ Wp (+bp) + x residual, LayerNorm, write Y ----
  f32x4v pacc[2][4];
#pragma unroll
  for (int rt = 0; rt < 2; rt++)
#pragma unroll
    for (int j2 = 0; j2 < 4; j2++) pacc[rt][j2] = (f32x4v){0.f, 0.f, 0.f, 0.f};
#pragma unroll
  for (int kk = 0; kk < 16; ++kk) {
    if (kk < 15) {
#pragma unroll
      for (int j2 = 0; j2 < 4; j2++)
        bfq[(kk + 1) & 1][j2] =
            *(const bf16x8v*)(Wpf + ((size_t)(w4 + j2) * 16 + kk + 1) * 512 + lane8);
    }
    const int swz = (((kk * 4 + quad) ^ sx7) << 4);
    bf16x8v af0 = *(const bf16x8v*)((const char*)Os + l15 * 1024 + swz);
    bf16x8v af1 = *(const bf16x8v*)((const char*)Os + (16 + l15) * 1024 + swz);
#pragma unroll
    for (int j2 = 0; j2 < 4; j2++) {
      pacc[0][j2] = MFMA(af0, bfq[kk & 1][j2], pacc[0][j2]);
      pacc[1][j2] = MFMA(af1, bfq[kk & 1][j2], pacc[1][j2]);
    }
  }

  const float* xr = x + ((size_t)b * 2048 + q0) * 512;
  float s1[2][4], s2[2][4];
#pragma unroll
  for (int rt = 0; rt < 2; rt++)
#pragma unroll
    for (int r = 0; r < 4; r++) { s1[rt][r] = 0.f; s2[rt][r] = 0.f; }
#pragma unroll
  for (int rt = 0; rt < 2; rt++)
#pragma unroll
    for (int j2 = 0; j2 < 4; j2++) {
      const int col = w * 64 + j2 * 16 + l15;
      const float bpv = bp[col];
#pragma unroll
      for (int r = 0; r < 4; r++) {
        const int row = rt * 16 + quad * 4 + r;
        float v = pacc[rt][j2][r] + bpv + xr[(size_t)row * 512 + col];
        pacc[rt][j2][r] = v;
        s1[rt][r] += v;
        s2[rt][r] += v * v;
      }
    }
#pragma unroll
  for (int off = 1; off < 16; off <<= 1)
#pragma unroll
    for (int rt = 0; rt < 2; rt++)
#pragma unroll
      for (int r = 0; r < 4; r++) {
        s1[rt][r] += __shfl_xor(s1[rt][r], off, 64);
        s2[rt][r] += __shfl_xor(s2[rt][r], off, 64);
      }
  if (l15 == 0)
#pragma unroll
    for (int rt = 0; rt < 2; rt++)
#pragma unroll
      for (int r = 0; r < 4; r++) {
        red[w * 32 + rt * 16 + quad * 4 + r] = s1[rt][r];
        red[256 + w * 32 + rt * 16 + quad * 4 + r] = s2[rt][r];
      }
  __syncthreads();
  float mu[2][4], rs[2][4];
#pragma unroll
  for (int rt = 0; rt < 2; rt++)
#pragma unroll
    for (int r = 0; r < 4; r++) {
      const int row = rt * 16 + quad * 4 + r;
      float a1 = 0.f, a2 = 0.f;
      for (int ww = 0; ww < 8; ww++) {
        a1 += red[ww * 32 + row];
        a2 += red[256 + ww * 32 + row];
      }
      mu[rt][r] = a1 * (1.0f / 512.0f);
      float var = a2 * (1.0f / 512.0f) - mu[rt][r] * mu[rt][r];
      rs[rt][r] = rsqrtf(var + 1e-5f);
    }
  float* Yr = Y + ((size_t)b * 2048 + q0) * 512;
#pragma unroll
  for (int rt = 0; rt < 2; rt++)
#pragma unroll
    for (int j2 = 0; j2 < 4; j2++) {
      const int col = w * 64 + j2 * 16 + l15;
      const float g = gamma[col], be = beta[col];
#pragma unroll
      for (int r = 0; r < 4; r++) {
        const int row = rt * 16 + quad * 4 + r;
        Yr[(size_t)row * 512 + col] = (pacc[rt][j2][r] - mu[rt][r]) * rs[rt][r] * g + be;
      }
    }
}

// ---------------------------------------------------------------------------
extern "C" void kernel_launch(void* const* d_in, const int* in_sizes, int n_in,
                              void* d_out, int out_size, void* d_ws, size_t ws_size,
                              hipStream_t stream) {
  const float* x = (const float*)d_in[0];
  const float* Wq = (const float*)d_in[1];
  const float* bq = (const float*)d_in[2];
  const float* Wk = (const float*)d_in[3];
  const float* bk = (const float*)d_in[4];
  const float* Wv = (const float*)d_in[5];
  const float* bv = (const float*)d_in[6];
  const float* Wp = (const float*)d_in[7];
  const float* bp = (const float*)d_in[8];
  const float* gamma = (const float*)d_in[9];
  const float* beta = (const float*)d_in[10];

  char* ws = (char*)d_ws;
  bf16* WT = (bf16*)ws;                                      // 2 MB
  size_t off = 4ull * 512 * 512 * 2;
  bf16* Qd = (bf16*)(ws + off); off += 16384ull * 512 * 2;   // 16 MB
  bf16* Kd = (bf16*)(ws + off); off += 16384ull * 512 * 2;   // 16 MB
  bf16* Vfd = (bf16*)(ws + off); off += 16384ull * 512 * 2;  // 16 MB (frag-packed)
  bf16* Wpf = (bf16*)(ws + off); off += 512ull * 1024;       // 0.5 MB (frag-packed Wp)

  float* Y = (float*)d_out;                     // f32 [8][2048][512]
  float* attn = Y + 8ull * 2048 * 512;          // f32 [8][2048][2048]
  bf16* Xb = (bf16*)d_out;  // bf16 X parked in Y region (consumed by qkv_gemm)

  hipLaunchKernelGGL(prep, dim3(2048), dim3(1024), 0, stream,
                     Wq, Wk, Wv, Wp, x, WT, Wpf, Xb);
  hipLaunchKernelGGL(qkv_gemm, dim3(4, 128, 3), dim3(256), 0, stream,
                     Xb, WT, bq, bk, bv, Qd, Kd, Vfd);
  hipLaunchKernelGGL(attn_kernel, dim3(512), dim3(512), 0, stream,
                     Qd, Kd, Vfd, attn, Wpf, bp, x, gamma, beta, Y);
}